// Round 4
// baseline (139.859 us; speedup 1.0000x reference)
//
#include <hip/hip_runtime.h>

#define LDIM 1024
#define NSHIFT 10

// One wave (64 lanes) per output row (b, i). Writes a 256-byte,
// 128B-aligned window of 64 dwords covering columns [i-10, i+10],
// computing band membership per lane. Everything else is already
// zeroed by the preceding memset.
__global__ __launch_bounds__(256) void band_writer(
    const int* __restrict__ mask, int* __restrict__ out, int n_rows)
{
    const int wave = (blockIdx.x << 2) | (threadIdx.x >> 6);  // global wave = row id
    if (wave >= n_rows) return;
    const int lane = threadIdx.x & 63;

    const int b = wave >> 10;
    const int i = wave & (LDIM - 1);
    const int* __restrict__ mrow = mask + b * LDIM;

    // 32-dword (128 B) aligned start covering i-10 .. i+10 within 64 dwords:
    // sd = (i-10) & ~31  =>  sd <= i-10 and sd+63 >= i+22 >= i+10.
    int sd = (i - NSHIFT) & ~31;
    if (sd < 0) sd = 0;

    const int j = sd + lane;   // column this lane owns
    int val = 0;
    if (j < LDIM) {
        const int d = j - i;
        if (d >= -NSHIFT && d <= NSHIFT) {
            const int lo = (d < 0) ? j : i;
            const int hi = (d < 0) ? i : j;
            int s = 0;
            for (int k = lo + 1; k <= hi; ++k) s += mrow[k];
            val = (s == 0) ? 1 : 0;
        }
        out[((size_t)wave << 10) + j] = val;
    }
}

extern "C" void kernel_launch(void* const* d_in, const int* in_sizes, int n_in,
                              void* d_out, int out_size, void* d_ws, size_t ws_size,
                              hipStream_t stream) {
    const int* mask = (const int*)d_in[0];
    int* out = (int*)d_out;

    const int B = in_sizes[0] / LDIM;   // 32
    const int n_rows = B * LDIM;        // 32768 rows = 32768 waves

    // Bulk zero at rocclr-fill rate (~6.5 TB/s measured on this device).
    hipMemsetAsync(d_out, 0, (size_t)out_size * sizeof(int), stream);

    // 4 waves per 256-thread block -> 8192 blocks.
    band_writer<<<(n_rows + 3) / 4, 256, 0, stream>>>(mask, out, n_rows);
}